// Round 6
// baseline (684.820 us; speedup 1.0000x reference)
//
#include <hip/hip_runtime.h>
#include <cstdint>
#include <cstddef>

#define BSZ 16
#define TLEN 2048
#define CDIM 1024
#define OUTDIM 512
#define MAXF 512

typedef _Float16 f16x8 __attribute__((ext_vector_type(8)));
typedef _Float16 f16x4 __attribute__((ext_vector_type(4)));
typedef float f32x16 __attribute__((ext_vector_type(16)));

// exact 2-term fp16 split: a = h0 + h1 * 2^-11  (h1 pre-scaled by 2^11)
struct h2pair { _Float16 h0, h1; };
__device__ __forceinline__ h2pair split2(float a) {
    h2pair o;
    o.h0 = (_Float16)a;
    float r = a - (float)o.h0;       // exact (Sterbenz)
    o.h1 = (_Float16)(r * 2048.0f);
    return o;
}

// ============================================================================
// k0: split Wd into fragment-linear fp16 planes (BF) + Wo into row-major
// planes. BF idx = p*1048576 + dut*131072 + kt*4096 + ntb2*2048 + ks*1024
//                 + nt*512 + lane*8   (lane = hi*32+l5; 8 halves per frag)
// Grid (8, 33): by<32 -> Wd path (dut=bx, kt=by); by==32 -> Wo path.
// ============================================================================
__global__ __launch_bounds__(128) void k0_split(
    const float* __restrict__ Wd, const float* __restrict__ Wo,
    _Float16* __restrict__ BF, _Float16* __restrict__ W0,
    _Float16* __restrict__ W1)
{
    const int bx = blockIdx.x;
    const int by = blockIdx.y;
    const int r = threadIdx.x;

    if (by == 32) {
        // Wo: 131072 float4s, 1024 lanes, 128 each, coalesced
        const int lane = bx * 128 + r;
        for (int i = 0; i < 128; i++) {
            const int i4 = i * 1024 + lane;
            float4 v = *(const float4*)(Wo + i4 * 4);
            f16x4 h0, h1;
            h2pair s0 = split2(v.x); h0[0] = s0.h0; h1[0] = s0.h1;
            h2pair s1 = split2(v.y); h0[1] = s1.h0; h1[1] = s1.h1;
            h2pair s2 = split2(v.z); h0[2] = s2.h0; h1[2] = s2.h1;
            h2pair s3 = split2(v.w); h0[3] = s3.h0; h1[3] = s3.h1;
            *(f16x4*)&W0[i4 * 4] = h0;
            *(f16x4*)&W1[i4 * 4] = h1;
        }
        return;
    }

    const int dut = bx, kt = by;
    const float* src = Wd + (size_t)(dut * 128 + r) * CDIM + kt * 32;
    float v[32];
#pragma unroll
    for (int j = 0; j < 8; j++) *(float4*)&v[j * 4] = *(const float4*)(src + j * 4);

    const int ntb2 = r >> 6, nt = (r >> 5) & 1, l5 = r & 31;
    const size_t base = (size_t)dut * 131072 + (size_t)kt * 4096 +
                        (size_t)ntb2 * 2048 + (size_t)nt * 512;
#pragma unroll
    for (int c = 0; c < 4; c++) {
        const int ks = c >> 1, hi = c & 1;
        f16x8 h0, h1;
#pragma unroll
        for (int j = 0; j < 8; j++) {
            h2pair s = split2(v[c * 8 + j]);
            h0[j] = s.h0;
            h1[j] = s.h1;
        }
        const size_t idx = base + (size_t)ks * 1024 + (size_t)(hi * 32 + l5) * 8;
        *(f16x8*)&BF[idx] = h0;
        *(f16x8*)&BF[1048576 + idx] = h1;
    }
}

// ============================================================================
// k1: g[row] = sum_du Wp[du]*relu(enc[row,:].Wd[du,:] + bd[du])
// fp16 2-term split, 3 MFMA products. A: LDS double-buffer (32 KB).
// B: fragment-direct global loads from BF (no LDS) — halves LDS traffic.
// XCD swizzle keeps the 8 du-blocks of a row-group on one XCD.
// ============================================================================
__global__ __launch_bounds__(256, 2) void k1_weight_gemm(
    const float* __restrict__ enc, const _Float16* __restrict__ BF,
    const float* __restrict__ bd, const float* __restrict__ Wp,
    float* __restrict__ g)
{
    // 2 buffers x (A0|A1 planes of 4096 halves) = 16384 halves = 32 KB
    __shared__ __align__(16) _Float16 lds[16384];

    const int tid = threadIdx.x;
    const int lane = tid & 63;
    const int wv = tid >> 6;
    const int l5 = lane & 31;
    const int hi = lane >> 5;
    const int mtb = (wv & 1) * 64;
    const int ntb = (wv >> 1) * 64;

    const int bx = blockIdx.x;
    const int xcd = bx & 7;
    const int j = bx >> 3;
    const int rg = xcd * 32 + (j >> 3);
    const int du = j & 7;
    const long row0 = (long)rg * 128;
    const int du0 = du * 128;

    const int sr = tid >> 1;          // A staging row
    const int sh = tid & 1;           // A staging k-half (16 floats)
    const float* aptr = enc + (row0 + sr) * (long)CDIM + sh * 16;

    // B fragment base for this wave: + p*1048576 + kt*4096 + ks*1024 + nt*512
    const _Float16* bbase = BF + (size_t)du * 131072 +
                            (size_t)(wv >> 1) * 2048 + (size_t)lane * 8;

    f32x16 acc[2][2], accc[2][2];
#pragma unroll
    for (int mt = 0; mt < 2; mt++)
#pragma unroll
        for (int nt = 0; nt < 2; nt++)
#pragma unroll
            for (int r = 0; r < 16; r++) { acc[mt][nt][r] = 0.f; accc[mt][nt][r] = 0.f; }

    float fa[16];

    // ---- pre-loop: stage A tile 0 into buf0, prefetch fa(tile 1) ----
#pragma unroll
    for (int jj = 0; jj < 4; jj++)
        *(float4*)&fa[jj * 4] = *(const float4*)(aptr + jj * 4);
    {
        f16x8 va0[2], va1[2];
#pragma unroll
        for (int c = 0; c < 2; c++)
#pragma unroll
            for (int jj = 0; jj < 8; jj++) {
                h2pair s = split2(fa[c * 8 + jj]);
                va0[c][jj] = s.h0;
                va1[c][jj] = s.h1;
            }
#pragma unroll
        for (int c = 0; c < 2; c++) {
            *(f16x8*)&lds[((sh * 2 + c) * 128 + sr) * 8] = va0[c];
            *(f16x8*)&lds[4096 + ((sh * 2 + c) * 128 + sr) * 8] = va1[c];
        }
    }
#pragma unroll
    for (int jj = 0; jj < 4; jj++)
        *(float4*)&fa[jj * 4] = *(const float4*)(aptr + 32 + jj * 4);

    for (int kt = 0; kt < 32; ++kt) {
        const int cur = (kt & 1) * 8192;
        const int nxt = ((kt & 1) ^ 1) * 8192;

        __syncthreads();   // A buf[cur] staged; buf[nxt] fully consumed

        // issue B fragment loads for THIS kt (regs; waitcnt before first use)
        f16x8 Bc[2][2][2];
#pragma unroll
        for (int p = 0; p < 2; p++)
#pragma unroll
            for (int ks = 0; ks < 2; ks++)
#pragma unroll
                for (int nt = 0; nt < 2; nt++)
                    Bc[p][ks][nt] = *(const f16x8*)(bbase + (size_t)p * 1048576 +
                                                    (size_t)kt * 4096 + ks * 1024 + nt * 512);

        if (kt < 31) {
            // split fa (= A tile kt+1) and write planes into nxt
            f16x8 va0[2], va1[2];
#pragma unroll
            for (int c = 0; c < 2; c++)
#pragma unroll
                for (int jj = 0; jj < 8; jj++) {
                    h2pair s = split2(fa[c * 8 + jj]);
                    va0[c][jj] = s.h0;
                    va1[c][jj] = s.h1;
                }
#pragma unroll
            for (int c = 0; c < 2; c++) {
                *(f16x8*)&lds[nxt + ((sh * 2 + c) * 128 + sr) * 8] = va0[c];
                *(f16x8*)&lds[nxt + 4096 + ((sh * 2 + c) * 128 + sr) * 8] = va1[c];
            }
            if (kt < 30) {
#pragma unroll
                for (int jj = 0; jj < 4; jj++)
                    *(float4*)&fa[jj * 4] = *(const float4*)(aptr + (kt + 2) * 32 + jj * 4);
            }
        }

        // ---- compute on cur ----
#pragma unroll
        for (int ks = 0; ks < 2; ks++) {
            const int ch = ks * 2 + hi;
            f16x8 A0[2], A1[2];
#pragma unroll
            for (int mt = 0; mt < 2; mt++) {
                const int row = mtb + mt * 32 + l5;
                A0[mt] = *(const f16x8*)&lds[cur + (ch * 128 + row) * 8];
                A1[mt] = *(const f16x8*)&lds[cur + 4096 + (ch * 128 + row) * 8];
            }
#pragma unroll
            for (int mt = 0; mt < 2; mt++)
#pragma unroll
                for (int nt = 0; nt < 2; nt++) {
                    acc[mt][nt] = __builtin_amdgcn_mfma_f32_32x32x16_f16(
                        A0[mt], Bc[0][ks][nt], acc[mt][nt], 0, 0, 0);
                    accc[mt][nt] = __builtin_amdgcn_mfma_f32_32x32x16_f16(
                        A0[mt], Bc[1][ks][nt], accc[mt][nt], 0, 0, 0);
                    accc[mt][nt] = __builtin_amdgcn_mfma_f32_32x32x16_f16(
                        A1[mt], Bc[0][ks][nt], accc[mt][nt], 0, 0, 0);
                }
        }
    }

    // epilogue: h = relu(acc_total + bd[n]); g += Wp[n]*h reduced over n
    float bdv[2], wpv[2];
#pragma unroll
    for (int nt = 0; nt < 2; nt++) {
        int n = du0 + ntb + nt * 32 + l5;
        bdv[nt] = bd[n];
        wpv[nt] = Wp[n];
    }
    float pm[2][16];
#pragma unroll
    for (int mt = 0; mt < 2; mt++)
#pragma unroll
        for (int r = 0; r < 16; r++) {
            float s = 0.f;
#pragma unroll
            for (int nt = 0; nt < 2; nt++) {
                float h = acc[mt][nt][r] + 4.8828125e-4f * accc[mt][nt][r] + bdv[nt];
                h = h > 0.f ? h : 0.f;
                s += wpv[nt] * h;
            }
            s += __shfl_xor(s, 1);
            s += __shfl_xor(s, 2);
            s += __shfl_xor(s, 4);
            s += __shfl_xor(s, 8);
            s += __shfl_xor(s, 16);
            pm[mt][r] = s;
        }
    float out = 0.f;
#pragma unroll
    for (int mt = 0; mt < 2; mt++)
#pragma unroll
        for (int r = 0; r < 16; r++)
            if (l5 == mt * 16 + r) out = pm[mt][r];
    const int mt_sel = l5 >> 4;
    const int r_sel = l5 & 15;
    const int row = mtb + mt_sel * 32 + (r_sel & 3) + 8 * (r_sel >> 2) + 4 * hi;
    atomicAdd(&g[row0 + row], out);
}

// ============================================================================
// k2: per-batch sigmoid + masked sum + scale + sequential scan (x8 unroll).
// ============================================================================
__global__ __launch_bounds__(256) void k2_scan(
    const float* __restrict__ g, const int* __restrict__ in_len,
    const int* __restrict__ tgt_len, const float* __restrict__ bp,
    float* __restrict__ c_a, float* __restrict__ c_b,
    int* __restrict__ fire_t, int* __restrict__ n_fired,
    float* __restrict__ out_mask, float* __restrict__ out_dur,
    float* __restrict__ out_qty)
{
    __shared__ float w[TLEN];
    __shared__ float ca[TLEN];
    __shared__ float cb[TLEN];
    __shared__ int fires[MAXF];
    __shared__ float ssum[256];
    __shared__ float s_scale;
    __shared__ int s_nf;

    const int b = blockIdx.x;
    const int tid = threadIdx.x;
    const int len = in_len[b];
    const float bpv = bp[0];

    float local = 0.f;
    for (int t = tid; t < TLEN; t += 256) {
        float gv = g[b * TLEN + t] + bpv;
        float s = 1.f / (1.f + expf(-gv));
        float ow = (t < len) ? s : 0.f;
        w[t] = ow;
        local += ow;
    }
    ssum[tid] = local;
    __syncthreads();
    for (int st = 128; st > 0; st >>= 1) {
        if (tid < st) ssum[tid] += ssum[tid + st];
        __syncthreads();
    }
    if (tid == 0) {
        float org_sum = ssum[0];
        out_qty[b] = org_sum;
        s_scale = (float)tgt_len[b] / (org_sum + 1e-8f);
    }
    __syncthreads();
    float scale = s_scale;
    for (int t = tid; t < TLEN; t += 256) w[t] *= scale;
    __syncthreads();

    if (tid == 0) {
        float accw = 0.f;
        int k = 0;
        int t = 0;
        for (; t + 8 <= len; t += 8) {
            float4 wa = *(const float4*)&w[t];
            float4 wb4 = *(const float4*)&w[t + 4];
            float wv8[8] = {wa.x, wa.y, wa.z, wa.w, wb4.x, wb4.y, wb4.z, wb4.w};
#pragma unroll
            for (int u = 0; u < 8; u++) {
                float wt = wv8[u];
                float aw = accw + wt;
                bool f = (aw >= 1.0f);
                float rem = 1.0f - accw;          // exact reference order
                float fb = wt - rem;
                ca[t + u] = f ? rem : wt;
                cb[t + u] = f ? fb : 0.f;
                fires[k & (MAXF - 1)] = t + u;
                k += f ? 1 : 0;
                accw = f ? fb : aw;
            }
        }
        for (; t < len; t++) {
            float wt = w[t];
            float aw = accw + wt;
            bool f = (aw >= 1.0f);
            float rem = 1.0f - accw;
            float fb = wt - rem;
            ca[t] = f ? rem : wt;
            cb[t] = f ? fb : 0.f;
            fires[k & (MAXF - 1)] = t;
            k += f ? 1 : 0;
            accw = f ? fb : aw;
        }
        s_nf = (k < MAXF) ? k : MAXF;
        n_fired[b] = s_nf;
    }
    __syncthreads();

    for (int t = tid; t < len; t += 256) {
        c_a[b * TLEN + t] = ca[t];
        c_b[b * TLEN + t] = cb[t];
    }
    const int nf = s_nf;
    for (int jj = tid; jj < nf; jj += 256) {
        int tj = fires[jj];
        fire_t[b * MAXF + jj] = tj;
        out_mask[b * TLEN + jj] = 1.0f;
        int prev = (jj == 0) ? 0 : fires[jj - 1];
        out_dur[b * TLEN + jj] = (float)(tj - prev);
    }
    if (tid == 0 && nf == 0) out_mask[b * TLEN] = 1.0f;
}

// ============================================================================
// k3a: compact fired frames (segmented weighted sums, ascending t), writing
// fp16 split planes row-major [b][frame][k]; rows >= n_fired zero-filled.
// ============================================================================
__global__ __launch_bounds__(256) void k3a_compact(
    const float* __restrict__ enc, const float* __restrict__ c_a,
    const float* __restrict__ c_b, const int* __restrict__ fire_t,
    const int* __restrict__ n_fired, _Float16* __restrict__ C0,
    _Float16* __restrict__ C1)
{
    const int b = blockIdx.y;
    const int k = blockIdx.x;
    const int tid = threadIdx.x;
    _Float16* d0 = C0 + ((size_t)b * MAXF + k) * CDIM + tid * 4;
    _Float16* d1 = C1 + ((size_t)b * MAXF + k) * CDIM + tid * 4;
    if (k >= n_fired[b]) {
        f16x4 z = {(_Float16)0.f, (_Float16)0.f, (_Float16)0.f, (_Float16)0.f};
        *(f16x4*)d0 = z;
        *(f16x4*)d1 = z;
        return;
    }
    const int tend = fire_t[b * MAXF + k];
    const int tprev = (k == 0) ? -1 : fire_t[b * MAXF + k - 1];
    float ax = 0.f, ay = 0.f, az = 0.f, aw = 0.f;
    const int tstart = (tprev < 0) ? 0 : tprev;
    for (int t = tstart; t <= tend; t++) {
        float coef = (t == tprev) ? c_b[b * TLEN + t] : c_a[b * TLEN + t];
        const float4 e = *(const float4*)(enc + ((size_t)b * TLEN + t) * CDIM + tid * 4);
        ax += coef * e.x;
        ay += coef * e.y;
        az += coef * e.z;
        aw += coef * e.w;
    }
    f16x4 h0, h1;
    h2pair s0 = split2(ax); h0[0] = s0.h0; h1[0] = s0.h1;
    h2pair s1 = split2(ay); h0[1] = s1.h0; h1[1] = s1.h1;
    h2pair s2 = split2(az); h0[2] = s2.h0; h1[2] = s2.h1;
    h2pair s3 = split2(aw); h0[3] = s3.h0; h1[3] = s3.h1;
    *(f16x4*)d0 = h0;
    *(f16x4*)d1 = h1;
}

// ============================================================================
// k3b: cif_outputs[b,j,o] — fp16-3 MFMA. Covers ALL 2048 rows; tiles fully
// past n_fired write zeros directly (replaces the 67 MB d_out memset).
// ============================================================================
__global__ __launch_bounds__(256, 2) void k3b_outproj(
    const _Float16* __restrict__ C0, const _Float16* __restrict__ C1,
    const _Float16* __restrict__ W0, const _Float16* __restrict__ W1,
    const int* __restrict__ n_fired, float* __restrict__ out0)
{
    __shared__ __align__(16) _Float16 lds[16384];

    const int b = blockIdx.z;
    const int nf = n_fired[b];
    const int j0 = blockIdx.x * 128;
    const int o0 = blockIdx.y * 128;
    const int tid = threadIdx.x;

    if (j0 >= nf) {
        // zero 128x128 output tile: 4096 float4s / 256 threads = 16 each
        const float4 z = make_float4(0.f, 0.f, 0.f, 0.f);
#pragma unroll
        for (int i = 0; i < 16; i++) {
            const int f = i * 256 + tid;
            const int row = f >> 5, col4 = f & 31;
            *(float4*)(out0 + ((size_t)b * TLEN + j0 + row) * OUTDIM + o0 + col4 * 4) = z;
        }
        return;
    }

    const int lane = tid & 63;
    const int wv = tid >> 6;
    const int l5 = lane & 31;
    const int hi = lane >> 5;
    const int mtb = (wv & 1) * 64;
    const int ntb = (wv >> 1) * 64;

    const int sr = tid >> 1;
    const int sh = tid & 1;
    const _Float16* a0p = C0 + ((size_t)b * MAXF + j0 + sr) * CDIM + sh * 16;
    const _Float16* a1p = C1 + ((size_t)b * MAXF + j0 + sr) * CDIM + sh * 16;
    const _Float16* b0p = W0 + (size_t)(o0 + sr) * CDIM + sh * 16;
    const _Float16* b1p = W1 + (size_t)(o0 + sr) * CDIM + sh * 16;

    f32x16 acc[2][2], accc[2][2];
#pragma unroll
    for (int mt = 0; mt < 2; mt++)
#pragma unroll
        for (int nt = 0; nt < 2; nt++)
#pragma unroll
            for (int r = 0; r < 16; r++) { acc[mt][nt][r] = 0.f; accc[mt][nt][r] = 0.f; }

    f16x8 xa0[2], xa1[2], xb0[2], xb1[2];
#pragma unroll
    for (int c = 0; c < 2; c++) {
        xa0[c] = *(const f16x8*)(a0p + c * 8);
        xa1[c] = *(const f16x8*)(a1p + c * 8);
        xb0[c] = *(const f16x8*)(b0p + c * 8);
        xb1[c] = *(const f16x8*)(b1p + c * 8);
    }

    for (int kt = 0; kt < 32; ++kt) {
        __syncthreads();
#pragma unroll
        for (int c = 0; c < 2; c++) {
            *(f16x8*)&lds[((sh * 2 + c) * 128 + sr) * 8] = xa0[c];
            *(f16x8*)&lds[4096 + ((sh * 2 + c) * 128 + sr) * 8] = xa1[c];
            *(f16x8*)&lds[8192 + ((sh * 2 + c) * 128 + sr) * 8] = xb0[c];
            *(f16x8*)&lds[12288 + ((sh * 2 + c) * 128 + sr) * 8] = xb1[c];
        }
        __syncthreads();
        if (kt < 31) {
            const int o = (kt + 1) * 32;
#pragma unroll
            for (int c = 0; c < 2; c++) {
                xa0[c] = *(const f16x8*)(a0p + o + c * 8);
                xa1[c] = *(const f16x8*)(a1p + o + c * 8);
                xb0[c] = *(const f16x8*)(b0p + o + c * 8);
                xb1[c] = *(const f16x8*)(b1p + o + c * 8);
            }
        }
#pragma unroll
        for (int ks = 0; ks < 2; ks++) {
            const int ch = ks * 2 + hi;
            f16x8 A0[2], A1[2], B0[2], B1[2];
#pragma unroll
            for (int mt = 0; mt < 2; mt++) {
                const int row = mtb + mt * 32 + l5;
                A0[mt] = *(const f16x8*)&lds[(ch * 128 + row) * 8];
                A1[mt] = *(const f16x8*)&lds[4096 + (ch * 128 + row) * 8];
            }
#pragma unroll
            for (int nt = 0; nt < 2; nt++) {
                const int row = ntb + nt * 32 + l5;
                B0[nt] = *(const f16x8*)&lds[8192 + (ch * 128 + row) * 8];
                B1[nt] = *(const f16x8*)&lds[12288 + (ch * 128 + row) * 8];
            }
#pragma unroll
            for (int mt = 0; mt < 2; mt++)
#pragma unroll
                for (int nt = 0; nt < 2; nt++) {
                    acc[mt][nt] = __builtin_amdgcn_mfma_f32_32x32x16_f16(
                        A0[mt], B0[nt], acc[mt][nt], 0, 0, 0);
                    accc[mt][nt] = __builtin_amdgcn_mfma_f32_32x32x16_f16(
                        A0[mt], B1[nt], accc[mt][nt], 0, 0, 0);
                    accc[mt][nt] = __builtin_amdgcn_mfma_f32_32x32x16_f16(
                        A1[mt], B0[nt], accc[mt][nt], 0, 0, 0);
                }
        }
    }

#pragma unroll
    for (int mt = 0; mt < 2; mt++)
#pragma unroll
        for (int nt = 0; nt < 2; nt++)
#pragma unroll
            for (int r = 0; r < 16; r++) {
                float val = acc[mt][nt][r] + 4.8828125e-4f * accc[mt][nt][r];
                int m = mtb + mt * 32 + (r & 3) + 8 * (r >> 2) + 4 * hi;
                int col = o0 + ntb + nt * 32 + l5;
                out0[((size_t)b * TLEN + j0 + m) * OUTDIM + col] = val;
            }
}

// ============================================================================
// Host launch
// ============================================================================
extern "C" void kernel_launch(void* const* d_in, const int* in_sizes, int n_in,
                              void* d_out, int out_size, void* d_ws, size_t ws_size,
                              hipStream_t stream)
{
    const float* enc = (const float*)d_in[0];
    const int* in_len = (const int*)d_in[1];
    const int* tgt_len = (const int*)d_in[2];
    const float* Wd = (const float*)d_in[3];
    const float* bd = (const float*)d_in[4];
    const float* Wp = (const float*)d_in[5];
    const float* bp = (const float*)d_in[6];
    const float* Wo = (const float*)d_in[7];

    char* ws = (char*)d_ws;
    float* g       = (float*)(ws + 0);             // 128 KB
    float* c_a     = (float*)(ws + 131072);        // 128 KB
    float* c_b     = (float*)(ws + 262144);        // 128 KB
    int* fire_t    = (int*)(ws + 393216);          // 32 KB
    int* n_fired   = (int*)(ws + 425984);          // 64 B
    _Float16* BF   = (_Float16*)(ws + 458752);     // 4 MB fragment-linear Wd
    _Float16* Wo0  = (_Float16*)(ws + 4653056);    // 1 MB row-major
    _Float16* Wo1  = (_Float16*)(ws + 5701632);    // 1 MB
    _Float16* C0   = (_Float16*)(ws + 6750208);    // 16 MB
    _Float16* C1   = (_Float16*)(ws + 23527424);   // 16 MB  (end ~40.3 MB)

    float* out0 = (float*)d_out;
    float* out_mask = out0 + (size_t)BSZ * TLEN * OUTDIM;
    float* out_dur = out_mask + (size_t)BSZ * TLEN;
    float* out_qty = out_dur + (size_t)BSZ * TLEN;

    (void)hipMemsetAsync(g, 0, 131072, stream);
    // only the mask/dur/qty tail needs zero-init (262 KB); k3b covers out0
    (void)hipMemsetAsync(out_mask, 0, (size_t)(BSZ * TLEN * 2 + BSZ) * 4, stream);

    k0_split<<<dim3(8, 33), 128, 0, stream>>>(Wd, Wo, BF, Wo0, Wo1);
    k1_weight_gemm<<<2048, 256, 0, stream>>>(enc, BF, bd, Wp, g);
    k2_scan<<<BSZ, 256, 0, stream>>>(g, in_len, tgt_len, bp, c_a, c_b,
                                     fire_t, n_fired, out_mask, out_dur, out_qty);
    k3a_compact<<<dim3(MAXF, BSZ), 256, 0, stream>>>(enc, c_a, c_b, fire_t,
                                                     n_fired, C0, C1);
    k3b_outproj<<<dim3(16, 4, BSZ), 256, 0, stream>>>(C0, C1, Wo0, Wo1,
                                                      n_fired, out0);
}